// Round 1
// baseline (31742.130 us; speedup 1.0000x reference)
//
#include <hip/hip_runtime.h>
#include <cstdint>
#include <cstddef>

// GRU_56607668961499: B=128, T=512, PRED=24, F=16, L=8, H=1024
// Strategy (round 1): host-loop of per-tick kernels; layers 0/1 pipelined in one
// launch; split-bf16 (hi+lo) MFMA 16x16x32 with fp32 accumulate for ~fp32 accuracy.
// Gate nonlinearity fused into GEMM epilogue; h stored as bf16 hi/lo planes.

typedef unsigned short ushort_t;
typedef short bf16x8 __attribute__((ext_vector_type(8)));   // 8 bf16 in 4 VGPRs
typedef float f32x4 __attribute__((ext_vector_type(4)));

__device__ __forceinline__ float bf2f(ushort_t u) {
  union { float f; uint32_t i; } v; v.i = ((uint32_t)u) << 16; return v.f;
}
__device__ __forceinline__ ushort_t f2bf(float f) {  // round-to-nearest-even
  union { float f; uint32_t i; } v; v.f = f;
  uint32_t x = v.i;
  return (ushort_t)((x + 0x7fffu + ((x >> 16) & 1u)) >> 16);
}
__device__ __forceinline__ float sigm(float x) { return 1.0f / (1.0f + __expf(-x)); }

// ---------------- weight split: fp32 -> bf16 hi + bf16 lo(residual) ----------
__global__ void split_kernel(const float* __restrict__ src, ushort_t* __restrict__ hi,
                             ushort_t* __restrict__ lo, int n) {
  int i = blockIdx.x * blockDim.x + threadIdx.x;
  if (i < n) {
    float f = src[i];
    ushort_t h = f2bf(f);
    hi[i] = h;
    lo[i] = f2bf(f - bf2f(h));
  }
}

// LDS weight buffer: 2 planes x 48 rows x 256 k, row stride 264 (pad -> 2-way
// bank aliasing only, which is free). Rows: g*16 + u_local, g in {r,z,n}.
#define WROW 264
#define WPLN (48 * WROW)  // 12672 ushorts per plane

__device__ __forceinline__ void stage_w(const ushort_t* __restrict__ whi,
                                        const ushort_t* __restrict__ wlo,
                                        ushort_t* wb, int Ubase, int kc, int tid) {
  // 2 planes * 48 rows * 32 (16B-units of 8 bf16) = 3072 units, 12 per thread
  for (int i = tid; i < 3072; i += 256) {
    int plane = (i >= 1536);
    int rem = i - plane * 1536;
    int row = rem >> 5;       // 0..47
    int k8 = rem & 31;        // 16B unit within 256-k chunk
    const ushort_t* gp = (plane ? wlo : whi)
        + (size_t)(((row >> 4) << 10) + Ubase + (row & 15)) * 1024 + (kc << 8) + (k8 << 3);
    *(uint4*)(wb + plane * WPLN + row * WROW + (k8 << 3)) = *(const uint4*)gp;
  }
}

// One K=256 chunk of the 3-gate GEMM for one wave (16 batch rows x 16 units x 3 gates),
// split-bf16: acc += Ahi*Bhi + Ahi*Blo + Alo*Bhi  (fp32 accumulate in MFMA).
__device__ __forceinline__ void run_chunk(const ushort_t* __restrict__ ahp,
                                          const ushort_t* __restrict__ alp,
                                          const ushort_t* wb, int lane,
                                          f32x4& aR, f32x4& aZ, f32x4& aN) {
  int kq = (lane >> 4) << 3;   // A/B fragment: k0 = quad*8
  int nr = lane & 15;
#pragma unroll
  for (int ks = 0; ks < 8; ++ks) {
    bf16x8 avh = *(const bf16x8*)(ahp + (ks << 5));
    bf16x8 avl = *(const bf16x8*)(alp + (ks << 5));
    int lk = (ks << 5) + kq;
    {
      const ushort_t* bp = wb + nr * WROW + lk;
      bf16x8 bh = *(const bf16x8*)(bp);
      bf16x8 bl = *(const bf16x8*)(bp + WPLN);
      aR = __builtin_amdgcn_mfma_f32_16x16x32_bf16(avh, bh, aR, 0, 0, 0);
      aR = __builtin_amdgcn_mfma_f32_16x16x32_bf16(avh, bl, aR, 0, 0, 0);
      aR = __builtin_amdgcn_mfma_f32_16x16x32_bf16(avl, bh, aR, 0, 0, 0);
    }
    {
      const ushort_t* bp = wb + (16 + nr) * WROW + lk;
      bf16x8 bh = *(const bf16x8*)(bp);
      bf16x8 bl = *(const bf16x8*)(bp + WPLN);
      aZ = __builtin_amdgcn_mfma_f32_16x16x32_bf16(avh, bh, aZ, 0, 0, 0);
      aZ = __builtin_amdgcn_mfma_f32_16x16x32_bf16(avh, bl, aZ, 0, 0, 0);
      aZ = __builtin_amdgcn_mfma_f32_16x16x32_bf16(avl, bh, aZ, 0, 0, 0);
    }
    {
      const ushort_t* bp = wb + (32 + nr) * WROW + lk;
      bf16x8 bh = *(const bf16x8*)(bp);
      bf16x8 bl = *(const bf16x8*)(bp + WPLN);
      aN = __builtin_amdgcn_mfma_f32_16x16x32_bf16(avh, bh, aN, 0, 0, 0);
      aN = __builtin_amdgcn_mfma_f32_16x16x32_bf16(avh, bl, aN, 0, 0, 0);
      aN = __builtin_amdgcn_mfma_f32_16x16x32_bf16(avl, bh, aN, 0, 0, 0);
    }
  }
}

// ------------------- encoder tick: L0 step t  +  L1 step t-1 -----------------
// grid = 256 blocks x 256 threads. blocks 0..127 -> layer0, 128..255 -> layer1.
// Block: 16 units (x3 gates) x 64 batch rows; wave = one 16-batch M-tile.
__global__ void gru_megatick(
    const float* __restrict__ feats, const float* __restrict__ labels,
    const float* __restrict__ wih0,
    const ushort_t* __restrict__ whh0_hi, const ushort_t* __restrict__ whh0_lo,
    const float* __restrict__ bih0, const float* __restrict__ bhh0,
    const ushort_t* __restrict__ wih1_hi, const ushort_t* __restrict__ wih1_lo,
    const ushort_t* __restrict__ whh1_hi, const ushort_t* __restrict__ whh1_lo,
    const float* __restrict__ bih1, const float* __restrict__ bhh1,
    const ushort_t* __restrict__ h0p_hi, const ushort_t* __restrict__ h0p_lo,
    ushort_t* __restrict__ h0o_hi, ushort_t* __restrict__ h0o_lo,
    const ushort_t* __restrict__ h1p_hi, const ushort_t* __restrict__ h1p_lo,
    ushort_t* __restrict__ h1o_hi, ushort_t* __restrict__ h1o_lo,
    int t, int l0on, int l1on) {
  int layer = blockIdx.x >> 7;
  if (layer == 0 && !l0on) return;
  if (layer == 1 && !l1on) return;
  int rb = blockIdx.x & 127;
  int Ubase = (rb >> 1) << 4;       // unit tile base (16 units)
  int Mblk = (rb & 1) << 6;         // batch half (64 rows)
  int tid = threadIdx.x;
  int lane = tid & 63;
  int wv = tid >> 6;

  __shared__ __align__(16) ushort_t wbuf[2 * WPLN];
  __shared__ float xs[64][25];      // x rows (L0 only), pad 25
  __shared__ float wih_s[48][25];   // Wih0 rows (L0 only)

  if (layer == 0) {
    for (int i = tid; i < 64 * 24; i += 256) {
      int bl = i / 24, k = i - bl * 24;
      int b = Mblk + bl;
      xs[bl][k] = (k < 16) ? feats[((size_t)b * 535 + t) * 16 + k]
                           : labels[((size_t)b * 512 + t) * 8 + (k - 16)];
    }
    for (int i = tid; i < 48 * 24; i += 256) {
      int rr = i / 24, k = i - rr * 24;
      int grow = ((rr >> 4) << 10) + Ubase + (rr & 15);
      wih_s[rr][k] = wih0[(size_t)grow * 24 + k];
    }
  }

  f32x4 aR = {0.f, 0.f, 0.f, 0.f}, aZ = {0.f, 0.f, 0.f, 0.f};
  f32x4 aNi = {0.f, 0.f, 0.f, 0.f}, aNh = {0.f, 0.f, 0.f, 0.f};
  int mrow = Mblk + (wv << 4) + (lane & 15);
  int kq = (lane >> 4) << 3;

  int nphase = (layer == 1) ? 2 : 1;
  for (int ph = 0; ph < nphase; ++ph) {
    const ushort_t *whi, *wlo, *ahi, *alo;
    bool to_ni;
    if (layer == 0)      { whi = whh0_hi; wlo = whh0_lo; ahi = h0p_hi; alo = h0p_lo; to_ni = false; }
    else if (ph == 0)    { whi = wih1_hi; wlo = wih1_lo; ahi = h0p_hi; alo = h0p_lo; to_ni = true;  }
    else                 { whi = whh1_hi; wlo = whh1_lo; ahi = h1p_hi; alo = h1p_lo; to_ni = false; }
    const ushort_t* arh = ahi + (size_t)mrow * 1024 + kq;
    const ushort_t* arl = alo + (size_t)mrow * 1024 + kq;
    for (int kc = 0; kc < 4; ++kc) {
      __syncthreads();  // protect wbuf from previous chunk readers
      stage_w(whi, wlo, wbuf, Ubase, kc, tid);
      __syncthreads();
      if (to_ni) run_chunk(arh + (kc << 8), arl + (kc << 8), wbuf, lane, aR, aZ, aNi);
      else       run_chunk(arh + (kc << 8), arl + (kc << 8), wbuf, lane, aR, aZ, aNh);
    }
  }

  // ---- fused GRU gate epilogue ----
  int u = Ubase + (lane & 15);
  const float* bih = (layer == 0) ? bih0 : bih1;
  const float* bhh = (layer == 0) ? bhh0 : bhh1;
  const ushort_t* hp_hi = (layer == 0) ? h0p_hi : h1p_hi;
  const ushort_t* hp_lo = (layer == 0) ? h0p_lo : h1p_lo;
  ushort_t* ho_hi = (layer == 0) ? h0o_hi : h1o_hi;
  ushort_t* ho_lo = (layer == 0) ? h0o_lo : h1o_lo;
  float bir = bih[u], bhr = bhh[u];
  float biz = bih[1024 + u], bhz = bhh[1024 + u];
  float bin_ = bih[2048 + u], bhn = bhh[2048 + u];
#pragma unroll
  for (int i = 0; i < 4; ++i) {
    int b = Mblk + (wv << 4) + ((lane >> 4) << 2) + i;  // D row = quad*4 + reg
    float giR = 0.f, giZ = 0.f, giN = 0.f;
    if (layer == 0) {
      const float* xr = &xs[b - Mblk][0];
#pragma unroll
      for (int k = 0; k < 24; ++k) {
        float xv = xr[k];
        giR += xv * wih_s[(lane & 15)][k];
        giZ += xv * wih_s[16 + (lane & 15)][k];
        giN += xv * wih_s[32 + (lane & 15)][k];
      }
    }
    float rg = sigm(aR[i] + giR + bir + bhr);
    float zg = sigm(aZ[i] + giZ + biz + bhz);
    float ng = tanhf(aNi[i] + giN + bin_ + rg * (aNh[i] + bhn));
    size_t off = (size_t)b * 1024 + u;
    float hpv = bf2f(hp_hi[off]) + bf2f(hp_lo[off]);
    float hn = (1.f - zg) * ng + zg * hpv;
    ushort_t hh = f2bf(hn);
    ho_hi[off] = hh;
    ho_lo[off] = f2bf(hn - bf2f(hh));
  }
}

// --------------------------- decoder tick (free-running) ---------------------
__global__ void gru_dectick(
    const float* __restrict__ feats,
    const float* __restrict__ dwih,
    const ushort_t* __restrict__ dwhh_hi, const ushort_t* __restrict__ dwhh_lo,
    const float* __restrict__ bih, const float* __restrict__ bhh,
    const float* __restrict__ p_prev,
    const ushort_t* __restrict__ hp_hi, const ushort_t* __restrict__ hp_lo,
    ushort_t* __restrict__ ho_hi, ushort_t* __restrict__ ho_lo, int d) {
  int rb = blockIdx.x;
  int Ubase = (rb >> 1) << 4;
  int Mblk = (rb & 1) << 6;
  int tid = threadIdx.x;
  int lane = tid & 63;
  int wv = tid >> 6;

  __shared__ __align__(16) ushort_t wbuf[2 * WPLN];
  __shared__ float xs[64][25];
  __shared__ float wih_s[48][25];

  for (int i = tid; i < 64 * 24; i += 256) {
    int bl = i / 24, k = i - bl * 24;
    int b = Mblk + bl;
    xs[bl][k] = (k < 16) ? feats[((size_t)b * 535 + 512 + d) * 16 + k]
                         : p_prev[b * 8 + (k - 16)];
  }
  for (int i = tid; i < 48 * 24; i += 256) {
    int rr = i / 24, k = i - rr * 24;
    int grow = ((rr >> 4) << 10) + Ubase + (rr & 15);
    wih_s[rr][k] = dwih[(size_t)grow * 24 + k];
  }

  f32x4 aR = {0.f, 0.f, 0.f, 0.f}, aZ = {0.f, 0.f, 0.f, 0.f}, aNh = {0.f, 0.f, 0.f, 0.f};
  int mrow = Mblk + (wv << 4) + (lane & 15);
  int kq = (lane >> 4) << 3;
  const ushort_t* arh = hp_hi + (size_t)mrow * 1024 + kq;
  const ushort_t* arl = hp_lo + (size_t)mrow * 1024 + kq;
  for (int kc = 0; kc < 4; ++kc) {
    __syncthreads();
    stage_w(dwhh_hi, dwhh_lo, wbuf, Ubase, kc, tid);
    __syncthreads();
    run_chunk(arh + (kc << 8), arl + (kc << 8), wbuf, lane, aR, aZ, aNh);
  }

  int u = Ubase + (lane & 15);
  float bir = bih[u], bhr = bhh[u];
  float biz = bih[1024 + u], bhz = bhh[1024 + u];
  float bin_ = bih[2048 + u], bhn = bhh[2048 + u];
#pragma unroll
  for (int i = 0; i < 4; ++i) {
    int b = Mblk + (wv << 4) + ((lane >> 4) << 2) + i;
    float giR = 0.f, giZ = 0.f, giN = 0.f;
    const float* xr = &xs[b - Mblk][0];
#pragma unroll
    for (int k = 0; k < 24; ++k) {
      float xv = xr[k];
      giR += xv * wih_s[(lane & 15)][k];
      giZ += xv * wih_s[16 + (lane & 15)][k];
      giN += xv * wih_s[32 + (lane & 15)][k];
    }
    float rg = sigm(aR[i] + giR + bir + bhr);
    float zg = sigm(aZ[i] + giZ + biz + bhz);
    float ng = tanhf(giN + bin_ + rg * (aNh[i] + bhn));
    size_t off = (size_t)b * 1024 + u;
    float hpv = bf2f(hp_hi[off]) + bf2f(hp_lo[off]);
    float hn = (1.f - zg) * ng + zg * hpv;
    ushort_t hh = f2bf(hn);
    ho_hi[off] = hh;
    ho_lo[off] = f2bf(hn - bf2f(hh));
  }
}

// -------------------------- FC head: p = h @ fcW.T + fcb ---------------------
__global__ void fc_kernel(const ushort_t* __restrict__ h_hi, const ushort_t* __restrict__ h_lo,
                          const float* __restrict__ fcW, const float* __restrict__ fcb,
                          float* __restrict__ out_slice, float* __restrict__ p_out) {
  int b = blockIdx.x;
  int tid = threadIdx.x;           // 64 threads = 1 wave
  int l = tid & 7, strip = tid >> 3;
  float s = 0.f;
  for (int j = 0; j < 128; ++j) {
    int k = strip * 128 + j;
    float hv = bf2f(h_hi[(size_t)b * 1024 + k]) + bf2f(h_lo[(size_t)b * 1024 + k]);
    s += hv * fcW[l * 1024 + k];
  }
  s += __shfl_xor(s, 8);
  s += __shfl_xor(s, 16);
  s += __shfl_xor(s, 32);
  if (tid < 8) {
    float v = s + fcb[l];
    out_slice[b * 8 + l] = v;
    p_out[b * 8 + l] = v;
  }
}

// ------------------------------------ host -----------------------------------
extern "C" void kernel_launch(void* const* d_in, const int* in_sizes, int n_in,
                              void* d_out, int out_size, void* d_ws, size_t ws_size,
                              hipStream_t stream) {
  (void)in_sizes; (void)n_in; (void)out_size; (void)ws_size;
  const float* feats = (const float*)d_in[0];
  const float* labels = (const float*)d_in[1];
  // d_in[2]=y (unused, teacher==0), d_in[3]=teacher (always 0 in setup)
  const float* wih0 = (const float*)d_in[4];
  const float* whh0 = (const float*)d_in[5];
  const float* bih0 = (const float*)d_in[6];
  const float* bhh0 = (const float*)d_in[7];
  const float* wih1 = (const float*)d_in[8];
  const float* whh1 = (const float*)d_in[9];
  const float* bih1 = (const float*)d_in[10];
  const float* bhh1 = (const float*)d_in[11];
  const float* dwih = (const float*)d_in[12];
  const float* dwhh = (const float*)d_in[13];
  const float* dbih = (const float*)d_in[14];
  const float* dbhh = (const float*)d_in[15];
  const float* fcW = (const float*)d_in[16];
  const float* fcb = (const float*)d_in[17];
  float* out = (float*)d_out;

  char* p = (char*)d_ws;
  auto alloc = [&](size_t bytes) { char* q = p; p += (bytes + 255) & ~(size_t)255; return q; };
  const size_t WP = (size_t)3072 * 1024;     // elements per weight plane
  ushort_t* whh0_hi = (ushort_t*)alloc(WP * 2);
  ushort_t* whh0_lo = (ushort_t*)alloc(WP * 2);
  ushort_t* wih1_hi = (ushort_t*)alloc(WP * 2);
  ushort_t* wih1_lo = (ushort_t*)alloc(WP * 2);
  ushort_t* whh1_hi = (ushort_t*)alloc(WP * 2);
  ushort_t* whh1_lo = (ushort_t*)alloc(WP * 2);
  ushort_t* dwhh_hi = (ushort_t*)alloc(WP * 2);
  ushort_t* dwhh_lo = (ushort_t*)alloc(WP * 2);
  const size_t HP = (size_t)128 * 1024;      // elements per h plane
  ushort_t* h0ring = (ushort_t*)alloc(4 * HP * 2);  // [slot][plane][HP]
  ushort_t* h1ring = (ushort_t*)alloc(4 * HP * 2);
  ushort_t* hdring = (ushort_t*)alloc(4 * HP * 2);
  float* pring = (float*)alloc(2 * 128 * 8 * 4);

  int sb = (int)((WP + 255) / 256);
  split_kernel<<<sb, 256, 0, stream>>>(whh0, whh0_hi, whh0_lo, (int)WP);
  split_kernel<<<sb, 256, 0, stream>>>(wih1, wih1_hi, wih1_lo, (int)WP);
  split_kernel<<<sb, 256, 0, stream>>>(whh1, whh1_hi, whh1_lo, (int)WP);
  split_kernel<<<sb, 256, 0, stream>>>(dwhh, dwhh_hi, dwhh_lo, (int)WP);
  hipMemsetAsync(h0ring, 0, 4 * HP * 2, stream);
  hipMemsetAsync(h1ring, 0, 4 * HP * 2, stream);

  for (int t = 0; t <= 512; ++t) {
    int s_h0p = (t + 1) & 1, s_h0o = t & 1;
    int s_h1p = t & 1, s_h1o = (t + 1) & 1;
    gru_megatick<<<256, 256, 0, stream>>>(
        feats, labels, wih0, whh0_hi, whh0_lo, bih0, bhh0,
        wih1_hi, wih1_lo, whh1_hi, whh1_lo, bih1, bhh1,
        h0ring + (size_t)s_h0p * 2 * HP, h0ring + (size_t)s_h0p * 2 * HP + HP,
        h0ring + (size_t)s_h0o * 2 * HP, h0ring + (size_t)s_h0o * 2 * HP + HP,
        h1ring + (size_t)s_h1p * 2 * HP, h1ring + (size_t)s_h1p * 2 * HP + HP,
        h1ring + (size_t)s_h1o * 2 * HP, h1ring + (size_t)s_h1o * 2 * HP + HP,
        t, (t < 512) ? 1 : 0, (t >= 1) ? 1 : 0);
  }

  // ps = h1_final @ fcW.T + fcb  (h1[511] lives in slot 1)
  const ushort_t* h1f = h1ring + 1 * 2 * HP;
  fc_kernel<<<128, 64, 0, stream>>>(h1f, h1f + HP, fcW, fcb, out, pring);

  for (int d = 0; d < 23; ++d) {
    const ushort_t* hp = (d == 0) ? (h1ring + 2 * HP) : (hdring + (size_t)(((d + 1) & 1)) * 2 * HP);
    ushort_t* ho = hdring + (size_t)(d & 1) * 2 * HP;
    gru_dectick<<<128, 256, 0, stream>>>(
        feats, dwih, dwhh_hi, dwhh_lo, dbih, dbhh,
        pring + (size_t)(d & 1) * 1024,
        hp, hp + HP, ho, ho + HP, d);
    fc_kernel<<<128, 64, 0, stream>>>(ho, ho + HP, fcW, fcb,
                                      out + (size_t)(d + 1) * 1024,
                                      pring + (size_t)((d + 1) & 1) * 1024);
  }
}